// Round 2
// baseline (3780.412 us; speedup 1.0000x reference)
//
#include <hip/hip_runtime.h>
#include <cstdint>

// ---------------------------------------------------------------------------
// MaskedDeepRNN fused: 2-layer masked LSTM, B=64 T=512 D_IN=256 H=512 G=2048.
// Single persistent kernel, 512 WGs (2/CU):
//   blocks   0..255 = layer 0, blocks 256..511 = layer 1.
// Islands of 32 WGs per 8-batch slice (blockIdx&7 -> XCD; L0 and L1 WGs of an
// island land on the SAME XCD, so all flag/ring traffic is L2-local).
// Layer-1 runs with lag >=1 behind layer-0 through an 8-slot L3 ring.
//
// Round-1 lesson: all-wave polling of 64B-strided flags saturated L2 with
// poll loads (64 lines / wave-poll) and regressed 1398->2053us. This round:
//   * flags PACKED at 4B stride: one 128B block per (layer,island); a wave
//     poll touches 2-4 lines instead of 64 (~16x less poll traffic).
//   * keep in-register cell math (gate-interleaved A rows), 2 barriers/step,
//     all-wave polling (no post-poll barrier).
//   * MFMA accumulation split into 4 independent chains (6-8 deep instead of
//     12-16) to cut dependent-MFMA latency exposure.
// ---------------------------------------------------------------------------

typedef _Float16 f16;
typedef _Float16 half8 __attribute__((ext_vector_type(8)));
typedef _Float16 half4v __attribute__((ext_vector_type(4)));
typedef float floatx4 __attribute__((ext_vector_type(4)));

#define B_ 64
#define T_ 512
#define DIN_ 256
#define H_ 512
#define G_ 2048

// workspace layout (bytes)
static const size_t OFF_FLAGS = 0;                              // 2 lay x 8 isl x 64 dw = 4 KB
static const size_t OFF_H0B   = 4096;                           // 8 isl x 8 slots x 8KB = 512 KB
static const size_t OFF_H1B   = OFF_H0B + 524288;               // 8 isl x 2 slots x 8KB = 128 KB
static const size_t OFF_WIH0  = OFF_H1B + 131072;
static const size_t OFF_WHH0  = OFF_WIH0 + (size_t)G_ * DIN_ * 2;
static const size_t OFF_WIH1  = OFF_WHH0 + (size_t)G_ * H_ * 2;
static const size_t OFF_WHH1  = OFF_WIH1 + (size_t)G_ * H_ * 2;
static const size_t OFF_B0    = OFF_WHH1 + (size_t)G_ * H_ * 2;
static const size_t OFF_B1    = OFF_B0 + 8192;
static const size_t ZERO_BYTES = OFF_WIH0;                      // flags + h rings

__device__ __forceinline__ uint32_t ald(const uint32_t* p) {
    return __hip_atomic_load(p, __ATOMIC_RELAXED, __HIP_MEMORY_SCOPE_AGENT);
}
__device__ __forceinline__ void ast(uint32_t* p, uint32_t v) {
    __hip_atomic_store(p, v, __ATOMIC_RELAXED, __HIP_MEMORY_SCOPE_AGENT);
}

// ---------------------------------------------------------------- prep ------
__global__ void k_maskw(const float* __restrict__ w, const float* __restrict__ m,
                        f16* __restrict__ o, int n4) {
    int i = blockIdx.x * 256 + threadIdx.x;
    if (i < n4) {
        const float4 wv = ((const float4*)w)[i];
        const float4 mv = ((const float4*)m)[i];
        half4v h = { (f16)(wv.x * mv.x), (f16)(wv.y * mv.y),
                     (f16)(wv.z * mv.z), (f16)(wv.w * mv.w) };
        ((half4v*)o)[i] = h;
    }
}

__global__ void k_bias(const float* __restrict__ a, const float* __restrict__ b,
                       float* __restrict__ o) {
    int i = blockIdx.x * 256 + threadIdx.x;
    if (i < G_) o[i] = a[i] + b[i];
}

// ------------------------------------------------------------ helpers -------
__device__ __forceinline__ void poll_flags(const uint32_t* ownF, uint32_t town,
                                           const uint32_t* crossF, uint32_t tcr,
                                           int lane) {
    // flags packed at 4B stride: lanes 0..31 watch the 32 own-island flags
    // (one 128B block), lanes 32..63 the partner layer's block.
    const uint32_t* p = (lane < 32) ? (ownF + lane) : (crossF + (lane - 32));
    const uint32_t tgt = (lane < 32) ? town : tcr;
    while (true) {
        const uint32_t v = ald(p);
        if (__all((int)(v >= tgt))) break;
        __builtin_amdgcn_s_sleep(1);
    }
}

__device__ __forceinline__ float lstm_cell(float gi, float gf, float gg, float go,
                                           float& c) {
    const float i_ = 1.f / (1.f + __expf(-gi));
    const float f_ = 1.f / (1.f + __expf(-gf));
    const float gc = fminf(fmaxf(gg, -20.f), 20.f);
    const float e2 = __expf(2.f * gc);
    const float g_ = (e2 - 1.f) / (e2 + 1.f);
    const float o_ = 1.f / (1.f + __expf(-go));
    c = f_ * c + i_ * g_;
    const float cc  = fminf(fmaxf(c, -20.f), 20.f);
    const float e2c = __expf(2.f * cc);
    return o_ * (e2c - 1.f) / (e2c + 1.f);
}

// -------------------------------------------------------- fused kernel ------
__global__ __launch_bounds__(256, 2) void fused_rnn(
    const float* __restrict__ x,
    const f16* __restrict__ Wih0, const f16* __restrict__ Whh0,
    const float* __restrict__ bs0,
    const f16* __restrict__ Wih1, const f16* __restrict__ Whh1,
    const float* __restrict__ bs1,
    float* __restrict__ dout,
    uint32_t* __restrict__ h0b,      // [8 isl][8 slots][2048 dw] f16 pairs
    uint32_t* __restrict__ h1b,      // [8 isl][2 slots][2048 dw]
    uint32_t* __restrict__ flags)    // [2 lay][8 isl][64 dw packed]
{
    __shared__ f16 bl0[8][520];            // B-operand: own-layer h
    __shared__ f16 bl1[8][520];            // B-operand: x (L0) or h0 (L1)

    const int tid  = threadIdx.x;
    const int bid  = blockIdx.x;
    const int isl  = bid & 7;              // -> XCD under round-robin
    const int mem  = (bid >> 3) & 31;
    const int layer = bid >> 8;
    const int jb = mem * 16, b0 = isl * 8;
    const int wave = tid >> 6, lane = tid & 63, lm = lane & 15, quad = lane >> 4;
    const int hrow = lm < 8 ? lm : 7;      // cols 8..15 duplicate row 7 (discarded)
    const int jj = (wave << 2) + quad;     // this lane's j-jb in the cell phase

    uint32_t* ownF   = flags + (size_t)(layer * 8 + isl) * 64;
    uint32_t* crossF = flags + (size_t)((1 - layer) * 8 + isl) * 64;
    uint32_t* h0i = h0b + (size_t)isl * 8 * 2048;
    uint32_t* h1i = h1b + (size_t)isl * 2 * 2048;

    if (layer == 0) {
        // ---- persistent A fragments, gate-interleaved rows: m = jsub*4+gt
        //      lane loads A row m=lm -> weight row (lm&3)*512 + jb + wave*4 + (lm>>2)
        half8 ah[16], ai[8];
        {
            const int row = (lm & 3) * 512 + jb + (wave << 2) + (lm >> 2);
            const f16* wr = Whh0 + (size_t)row * H_ + quad * 8;
            const f16* xr = Wih0 + (size_t)row * DIN_ + quad * 8;
#pragma unroll
            for (int kk = 0; kk < 16; ++kk) ah[kk] = *(const half8*)(wr + kk * 32);
#pragma unroll
            for (int kk = 0; kk < 8; ++kk)  ai[kk] = *(const half8*)(xr + kk * 32);
        }
        float bias[4];
#pragma unroll
        for (int g = 0; g < 4; ++g) bias[g] = bs0[g * 512 + jb + jj];
        float c = 0.f;
        // x[t] slice for this island: thread -> (batch=tid>>5, k0=(tid&31)*8)
        const float* xp = x + (size_t)(b0 + (tid >> 5)) * T_ * DIN_ + (tid & 31) * 8;
        float4 xa = *(const float4*)xp;            // x[0] preloaded
        float4 xb = *(const float4*)(xp + 4);

        for (int t = 0; t < T_; ++t) {
            // own peers done with step t-1; L1 done with step t-8 (ring safety)
            poll_flags(ownF, (uint32_t)t, crossF,
                       t >= 7 ? (uint32_t)(t - 7) : 0u, lane);
            // ---- stage h0[t-1] (ring slot (t-1)&7) + x[t]; prefetch x[t+1]
            // (prev-step MFMA reads were drained by the end-of-step barrier)
            {
                const uint32_t* hb = h0i + (size_t)((t + 7) & 7) * 2048;
                uint32_t va[8];
#pragma unroll
                for (int i = 0; i < 8; ++i) va[i] = ald(hb + i * 256 + tid);
                half8 hx = { (f16)xa.x, (f16)xa.y, (f16)xa.z, (f16)xa.w,
                             (f16)xb.x, (f16)xb.y, (f16)xb.z, (f16)xb.w };
                *(half8*)&bl1[tid >> 5][(tid & 31) * 8] = hx;
                const size_t tn = (size_t)(t + 1 < T_ ? t + 1 : t) * DIN_;
                xa = *(const float4*)(xp + tn);    // L2/L3-hot, hides under h latency
                xb = *(const float4*)(xp + tn + 4);
#pragma unroll
                for (int i = 0; i < 8; ++i) {
                    const int u = i * 256 + tid;
                    *(uint32_t*)&bl0[u >> 8][(u & 255) * 2] = va[i];
                }
            }
            __syncthreads();
            // ---- MFMA: full K per wave, 4 independent acc chains (6 deep)
            floatx4 acc[4] = {};
            {
                const f16* br0 = &bl0[hrow][quad * 8];
                const f16* br1 = &bl1[hrow][quad * 8];
#pragma unroll
                for (int kk = 0; kk < 16; ++kk)
                    acc[kk & 3] = __builtin_amdgcn_mfma_f32_16x16x32_f16(
                        ah[kk], *(const half8*)(br0 + kk * 32), acc[kk & 3], 0, 0, 0);
#pragma unroll
                for (int kk = 0; kk < 8; ++kk)
                    acc[kk & 3] = __builtin_amdgcn_mfma_f32_16x16x32_f16(
                        ai[kk], *(const half8*)(br1 + kk * 32), acc[kk & 3], 0, 0, 0);
            }
            const floatx4 av = (acc[0] + acc[1]) + (acc[2] + acc[3]);
            // ---- gate math fully in-register: lane = (batch=lm, j=jb+jj),
            //      av[r] = gate r (rows were gate-interleaved)
            const float hn = lstm_cell(av[0] + bias[0], av[1] + bias[1],
                                       av[2] + bias[2], av[3] + bias[3], c);
            const float ho = __shfl_xor(hn, 16);   // partner quad -> j+1
            if (!(quad & 1) && lm < 8) {
                union { f16 h[2]; uint32_t u; } pk;
                pk.h[0] = (f16)hn; pk.h[1] = (f16)ho;
                ast(h0i + (size_t)(t & 7) * 2048 + (lm * H_ + jb + jj) / 2, pk.u);
            }
            __syncthreads();                       // drains h stores (vmcnt 0)
            if (tid == 0) ast(ownF + mem, (uint32_t)(t + 1));
        }
    } else {
        // ---- layer 1: Whh1 + Wih1, both K=512, gates = h1.Whh1 + h0.Wih1
        half8 ah[16], ai[16];
        {
            const int row = (lm & 3) * 512 + jb + (wave << 2) + (lm >> 2);
            const f16* wr = Whh1 + (size_t)row * H_ + quad * 8;
            const f16* xr = Wih1 + (size_t)row * H_ + quad * 8;
#pragma unroll
            for (int kk = 0; kk < 16; ++kk) {
                ah[kk] = *(const half8*)(wr + kk * 32);
                ai[kk] = *(const half8*)(xr + kk * 32);
            }
        }
        float bias[4];
#pragma unroll
        for (int g = 0; g < 4; ++g) bias[g] = bs1[g * 512 + jb + jj];
        float c = 0.f;

        for (int t = 0; t < T_; ++t) {
            // own peers done with step t-1; L0 has published h0[t] (flag t+1)
            poll_flags(ownF, (uint32_t)t, crossF, (uint32_t)(t + 1), lane);
            // ---- stage h1[t-1] (parity) + h0[t] (ring slot t&7)
            {
                const uint32_t* hb = h1i + (size_t)((t + 1) & 1) * 2048;
                const uint32_t* gb = h0i + (size_t)(t & 7) * 2048;
                uint32_t va[8], vb[8];
#pragma unroll
                for (int i = 0; i < 8; ++i) va[i] = ald(hb + i * 256 + tid);
#pragma unroll
                for (int i = 0; i < 8; ++i) vb[i] = ald(gb + i * 256 + tid);
#pragma unroll
                for (int i = 0; i < 8; ++i) {
                    const int u = i * 256 + tid;
                    *(uint32_t*)&bl0[u >> 8][(u & 255) * 2] = va[i];
                    *(uint32_t*)&bl1[u >> 8][(u & 255) * 2] = vb[i];
                }
            }
            __syncthreads();
            // ---- MFMA: 4 independent acc chains (8 deep)
            floatx4 acc[4] = {};
            {
                const f16* br0 = &bl0[hrow][quad * 8];
                const f16* br1 = &bl1[hrow][quad * 8];
#pragma unroll
                for (int kk = 0; kk < 16; ++kk) {
                    acc[kk & 3] = __builtin_amdgcn_mfma_f32_16x16x32_f16(
                        ah[kk], *(const half8*)(br0 + kk * 32), acc[kk & 3], 0, 0, 0);
                    acc[kk & 3] = __builtin_amdgcn_mfma_f32_16x16x32_f16(
                        ai[kk], *(const half8*)(br1 + kk * 32), acc[kk & 3], 0, 0, 0);
                }
            }
            const floatx4 av = (acc[0] + acc[1]) + (acc[2] + acc[3]);
            const float hn = lstm_cell(av[0] + bias[0], av[1] + bias[1],
                                       av[2] + bias[2], av[3] + bias[3], c);
            const float ho = __shfl_xor(hn, 16);
            if (!(quad & 1) && lm < 8) {
                union { f16 h[2]; uint32_t u; } pk;
                pk.h[0] = (f16)hn; pk.h[1] = (f16)ho;
                ast(h1i + (size_t)(t & 1) * 2048 + (lm * H_ + jb + jj) / 2, pk.u);
            }
            if (t == T_ - 1 && lm < 8)
                dout[(size_t)(b0 + lm) * H_ + jb + jj] = hn;
            __syncthreads();                       // drains h stores (vmcnt 0)
            if (tid == 0) ast(ownF + mem, (uint32_t)(t + 1));
        }
    }
}

// ------------------------------------------------------------ launcher ------
extern "C" void kernel_launch(void* const* d_in, const int* in_sizes, int n_in,
                              void* d_out, int out_size, void* d_ws, size_t ws_size,
                              hipStream_t stream) {
    const float* x    = (const float*)d_in[0];
    const float* Wih0 = (const float*)d_in[1];
    const float* Whh0 = (const float*)d_in[2];
    const float* bih0 = (const float*)d_in[3];
    const float* bhh0 = (const float*)d_in[4];
    const float* mih0 = (const float*)d_in[5];
    const float* mhh0 = (const float*)d_in[6];
    const float* Wih1 = (const float*)d_in[7];
    const float* Whh1 = (const float*)d_in[8];
    const float* bih1 = (const float*)d_in[9];
    const float* bhh1 = (const float*)d_in[10];
    const float* mih1 = (const float*)d_in[11];
    const float* mhh1 = (const float*)d_in[12];

    char* ws = (char*)d_ws;
    uint32_t* flags = (uint32_t*)(ws + OFF_FLAGS);
    uint32_t* h0b   = (uint32_t*)(ws + OFF_H0B);
    uint32_t* h1b   = (uint32_t*)(ws + OFF_H1B);
    f16*   wih0 = (f16*)(ws + OFF_WIH0);
    f16*   whh0 = (f16*)(ws + OFF_WHH0);
    f16*   wih1 = (f16*)(ws + OFF_WIH1);
    f16*   whh1 = (f16*)(ws + OFF_WHH1);
    float* bs0  = (float*)(ws + OFF_B0);
    float* bs1  = (float*)(ws + OFF_B1);
    float* out  = (float*)d_out;

    // zero flags + h rings (ws is re-poisoned before every timed call)
    hipMemsetAsync(ws, 0, ZERO_BYTES, stream);

    k_maskw<<<512,  256, 0, stream>>>(Wih0, mih0, wih0, G_ * DIN_ / 4);
    k_maskw<<<1024, 256, 0, stream>>>(Whh0, mhh0, whh0, G_ * H_ / 4);
    k_maskw<<<1024, 256, 0, stream>>>(Wih1, mih1, wih1, G_ * H_ / 4);
    k_maskw<<<1024, 256, 0, stream>>>(Whh1, mhh1, whh1, G_ * H_ / 4);
    k_bias<<<8, 256, 0, stream>>>(bih0, bhh0, bs0);
    k_bias<<<8, 256, 0, stream>>>(bih1, bhh1, bs1);

    fused_rnn<<<512, 256, 0, stream>>>(x, wih0, whh0, bs0, wih1, whh1, bs1,
                                       out, h0b, h1b, flags);

    (void)in_sizes; (void)n_in; (void)out_size; (void)ws_size;
}

// Round 3
// 1604.723 us; speedup vs baseline: 2.3558x; 2.3558x over previous
//
#include <hip/hip_runtime.h>
#include <cstdint>

// ---------------------------------------------------------------------------
// MaskedDeepRNN fused: 2-layer masked LSTM, B=64 T=512 D_IN=256 H=512 G=2048.
// Single persistent kernel, 256 WGs (1/CU):
//   blocks   0..127 = layer 0, blocks 128..255 = layer 1.
// Islands of 16 WGs per 8-batch slice (blockIdx&7 -> XCD; L0/L1 WGs of an
// island share the XCD -> flag/ring traffic is L2-local).
// Layer-1 lags layer-0 by >=1 step through an 8-slot L3 ring.
//
// Round-1/2 lesson: all-wave polling regressed badly (poll storms on L2).
// This round reverts to the PROVEN sync (wave0-only poll, 64B-stride flags,
// post-poll barrier) and instead halves the sync fan-in: 16 WGs per
// (island,layer), each covering 32 j (two 16-row gate-interleaved A-tiles
// per wave). Kept from R1: in-register cell math (no LDS partial reduction,
// no serial gate section), 3 barriers/step, independent MFMA chains; B-frag
// LDS reads are shared by both tiles (24 ds_reads feed 48-64 MFMAs).
// ---------------------------------------------------------------------------

typedef _Float16 f16;
typedef _Float16 half8 __attribute__((ext_vector_type(8)));
typedef _Float16 half4v __attribute__((ext_vector_type(4)));
typedef float floatx4 __attribute__((ext_vector_type(4)));

#define B_ 64
#define T_ 512
#define DIN_ 256
#define H_ 512
#define G_ 2048

// workspace layout (bytes)
static const size_t OFF_FLAGS = 0;                              // 2 lay x 8 isl x 16 flags x 64B = 16 KB
static const size_t OFF_H0B   = 16384;                          // 8 isl x 8 slots x 8KB = 512 KB
static const size_t OFF_H1B   = OFF_H0B + 524288;               // 8 isl x 2 slots x 8KB = 128 KB
static const size_t OFF_WIH0  = OFF_H1B + 131072;
static const size_t OFF_WHH0  = OFF_WIH0 + (size_t)G_ * DIN_ * 2;
static const size_t OFF_WIH1  = OFF_WHH0 + (size_t)G_ * H_ * 2;
static const size_t OFF_WHH1  = OFF_WIH1 + (size_t)G_ * H_ * 2;
static const size_t OFF_B0    = OFF_WHH1 + (size_t)G_ * H_ * 2;
static const size_t OFF_B1    = OFF_B0 + 8192;
static const size_t ZERO_BYTES = OFF_WIH0;                      // flags + h rings

__device__ __forceinline__ uint32_t ald(const uint32_t* p) {
    return __hip_atomic_load(p, __ATOMIC_RELAXED, __HIP_MEMORY_SCOPE_AGENT);
}
__device__ __forceinline__ void ast(uint32_t* p, uint32_t v) {
    __hip_atomic_store(p, v, __ATOMIC_RELAXED, __HIP_MEMORY_SCOPE_AGENT);
}

// ---------------------------------------------------------------- prep ------
__global__ void k_maskw(const float* __restrict__ w, const float* __restrict__ m,
                        f16* __restrict__ o, int n4) {
    int i = blockIdx.x * 256 + threadIdx.x;
    if (i < n4) {
        const float4 wv = ((const float4*)w)[i];
        const float4 mv = ((const float4*)m)[i];
        half4v h = { (f16)(wv.x * mv.x), (f16)(wv.y * mv.y),
                     (f16)(wv.z * mv.z), (f16)(wv.w * mv.w) };
        ((half4v*)o)[i] = h;
    }
}

__global__ void k_bias(const float* __restrict__ a, const float* __restrict__ b,
                       float* __restrict__ o) {
    int i = blockIdx.x * 256 + threadIdx.x;
    if (i < G_) o[i] = a[i] + b[i];
}

// ------------------------------------------------------------ helpers -------
__device__ __forceinline__ void poll_flags(const uint32_t* ownF, uint32_t town,
                                           const uint32_t* crossF, uint32_t tcr,
                                           int lane) {
    // 16 flags per (layer,island), 64B stride. lanes 0..15 watch own flags,
    // lanes 16..31 the partner layer's; lanes 32..63 duplicate (same lines).
    const int l15 = lane & 15;
    const uint32_t* p = (lane & 16) ? (crossF + (size_t)l15 * 16)
                                    : (ownF + (size_t)l15 * 16);
    const uint32_t tgt = (lane & 16) ? tcr : town;
    while (true) {
        const uint32_t v = ald(p);
        if (__all((int)(v >= tgt))) break;
        __builtin_amdgcn_s_sleep(1);
    }
}

__device__ __forceinline__ float lstm_cell(float gi, float gf, float gg, float go,
                                           float& c) {
    const float i_ = 1.f / (1.f + __expf(-gi));
    const float f_ = 1.f / (1.f + __expf(-gf));
    const float gc = fminf(fmaxf(gg, -20.f), 20.f);
    const float e2 = __expf(2.f * gc);
    const float g_ = (e2 - 1.f) / (e2 + 1.f);
    const float o_ = 1.f / (1.f + __expf(-go));
    c = f_ * c + i_ * g_;
    const float cc  = fminf(fmaxf(c, -20.f), 20.f);
    const float e2c = __expf(2.f * cc);
    return o_ * (e2c - 1.f) / (e2c + 1.f);
}

// -------------------------------------------------------- fused kernel ------
__global__ __launch_bounds__(256, 1) void fused_rnn(
    const float* __restrict__ x,
    const f16* __restrict__ Wih0, const f16* __restrict__ Whh0,
    const float* __restrict__ bs0,
    const f16* __restrict__ Wih1, const f16* __restrict__ Whh1,
    const float* __restrict__ bs1,
    float* __restrict__ dout,
    uint32_t* __restrict__ h0b,      // [8 isl][8 slots][2048 dw] f16 pairs
    uint32_t* __restrict__ h1b,      // [8 isl][2 slots][2048 dw]
    uint32_t* __restrict__ flags)    // [2 lay][8 isl][16 x 16 dw]
{
    __shared__ f16 bl0[8][520];            // B-operand: own-layer h
    __shared__ f16 bl1[8][520];            // B-operand: x (L0) or h0 (L1)

    const int tid  = threadIdx.x;
    const int bid  = blockIdx.x;
    const int isl  = bid & 7;              // -> XCD under round-robin
    const int mem  = (bid >> 3) & 15;      // 16 WGs per (layer,island)
    const int layer = bid >> 7;
    const int jb = mem * 32, b0 = isl * 8;
    const int wave = tid >> 6, lane = tid & 63, lm = lane & 15, quad = lane >> 4;
    const int hrow = lm < 8 ? lm : 7;      // cols 8..15 duplicate row 7 (discarded)
    const int jw = jb + (wave << 3);       // wave's j-base (8 j per wave, 2 tiles)

    uint32_t* ownF   = flags + (size_t)(layer * 8 + isl) * 256;
    uint32_t* crossF = flags + (size_t)((1 - layer) * 8 + isl) * 256;
    uint32_t* h0i = h0b + (size_t)isl * 8 * 2048;
    uint32_t* h1i = h1b + (size_t)isl * 2 * 2048;

    if (layer == 0) {
        // ---- persistent A fragments, 2 tiles of 16 gate-interleaved rows:
        //      tile tt row m=lm -> weight row (lm&3)*512 + jw + tt*4 + (lm>>2)
        half8 ah[2][16], ai[2][8];
#pragma unroll
        for (int tt = 0; tt < 2; ++tt) {
            const int row = (lm & 3) * 512 + jw + tt * 4 + (lm >> 2);
            const f16* wr = Whh0 + (size_t)row * H_ + quad * 8;
            const f16* xr = Wih0 + (size_t)row * DIN_ + quad * 8;
#pragma unroll
            for (int kk = 0; kk < 16; ++kk) ah[tt][kk] = *(const half8*)(wr + kk * 32);
#pragma unroll
            for (int kk = 0; kk < 8; ++kk)  ai[tt][kk] = *(const half8*)(xr + kk * 32);
        }
        float bias[2][4];
#pragma unroll
        for (int tt = 0; tt < 2; ++tt)
#pragma unroll
            for (int g = 0; g < 4; ++g)
                bias[tt][g] = bs0[g * 512 + jw + tt * 4 + quad];
        float c[2] = {0.f, 0.f};
        // x[t] slice for this island: thread -> (batch=tid>>5, k0=(tid&31)*8)
        const float* xp = x + (size_t)(b0 + (tid >> 5)) * T_ * DIN_ + (tid & 31) * 8;
        float4 xa = *(const float4*)xp;            // x[0] preloaded
        float4 xb = *(const float4*)(xp + 4);

        for (int t = 0; t < T_; ++t) {
            // own peers done with step t-1; L1 done with step t-8 (ring safety)
            if (wave == 0)
                poll_flags(ownF, (uint32_t)t, crossF,
                           t >= 7 ? (uint32_t)(t - 7) : 0u, lane);
            __syncthreads();
            // ---- stage h0[t-1] (ring slot (t-1)&7) + x[t]; prefetch x[t+1]
            {
                const uint32_t* hb = h0i + (size_t)((t + 7) & 7) * 2048;
                uint32_t va[8];
#pragma unroll
                for (int i = 0; i < 8; ++i) va[i] = ald(hb + i * 256 + tid);
                half8 hx = { (f16)xa.x, (f16)xa.y, (f16)xa.z, (f16)xa.w,
                             (f16)xb.x, (f16)xb.y, (f16)xb.z, (f16)xb.w };
                *(half8*)&bl1[tid >> 5][(tid & 31) * 8] = hx;
                const size_t tn = (size_t)(t + 1 < T_ ? t + 1 : t) * DIN_;
                xa = *(const float4*)(xp + tn);    // L2/L3-hot
                xb = *(const float4*)(xp + tn + 4);
#pragma unroll
                for (int i = 0; i < 8; ++i) {
                    const int u = i * 256 + tid;
                    *(uint32_t*)&bl0[u >> 8][(u & 255) * 2] = va[i];
                }
            }
            __syncthreads();
            // ---- MFMA: 2 tiles x full K; shared B loads; 8 indep chains
            floatx4 acc[2][4] = {};
            {
                const f16* br0 = &bl0[hrow][quad * 8];
                const f16* br1 = &bl1[hrow][quad * 8];
#pragma unroll
                for (int kk = 0; kk < 16; ++kk) {
                    const half8 bv = *(const half8*)(br0 + kk * 32);
                    acc[0][kk & 3] = __builtin_amdgcn_mfma_f32_16x16x32_f16(
                        ah[0][kk], bv, acc[0][kk & 3], 0, 0, 0);
                    acc[1][kk & 3] = __builtin_amdgcn_mfma_f32_16x16x32_f16(
                        ah[1][kk], bv, acc[1][kk & 3], 0, 0, 0);
                }
#pragma unroll
                for (int kk = 0; kk < 8; ++kk) {
                    const half8 bv = *(const half8*)(br1 + kk * 32);
                    acc[0][kk & 3] = __builtin_amdgcn_mfma_f32_16x16x32_f16(
                        ai[0][kk], bv, acc[0][kk & 3], 0, 0, 0);
                    acc[1][kk & 3] = __builtin_amdgcn_mfma_f32_16x16x32_f16(
                        ai[1][kk], bv, acc[1][kk & 3], 0, 0, 0);
                }
            }
            // ---- gate math in-register: lane = (batch=lm, j=jw+tt*4+quad)
#pragma unroll
            for (int tt = 0; tt < 2; ++tt) {
                const floatx4 av = (acc[tt][0] + acc[tt][1]) + (acc[tt][2] + acc[tt][3]);
                const float hn = lstm_cell(av[0] + bias[tt][0], av[1] + bias[tt][1],
                                           av[2] + bias[tt][2], av[3] + bias[tt][3],
                                           c[tt]);
                const float ho = __shfl_xor(hn, 16);   // partner quad -> j+1
                if (!(quad & 1) && lm < 8) {
                    union { f16 h[2]; uint32_t u; } pk;
                    pk.h[0] = (f16)hn; pk.h[1] = (f16)ho;
                    ast(h0i + (size_t)(t & 7) * 2048 +
                        (lm * H_ + jw + tt * 4 + quad) / 2, pk.u);
                }
            }
            __syncthreads();                       // drains h stores (vmcnt 0)
            if (tid == 0) ast(ownF + mem * 16, (uint32_t)(t + 1));
        }
    } else {
        // ---- layer 1: Whh1 + Wih1, both K=512, gates = h1.Whh1 + h0.Wih1
        half8 ah[2][16], ai[2][16];
#pragma unroll
        for (int tt = 0; tt < 2; ++tt) {
            const int row = (lm & 3) * 512 + jw + tt * 4 + (lm >> 2);
            const f16* wr = Whh1 + (size_t)row * H_ + quad * 8;
            const f16* xr = Wih1 + (size_t)row * H_ + quad * 8;
#pragma unroll
            for (int kk = 0; kk < 16; ++kk) {
                ah[tt][kk] = *(const half8*)(wr + kk * 32);
                ai[tt][kk] = *(const half8*)(xr + kk * 32);
            }
        }
        float bias[2][4];
#pragma unroll
        for (int tt = 0; tt < 2; ++tt)
#pragma unroll
            for (int g = 0; g < 4; ++g)
                bias[tt][g] = bs1[g * 512 + jw + tt * 4 + quad];
        float c[2] = {0.f, 0.f};

        for (int t = 0; t < T_; ++t) {
            // own peers done with step t-1; L0 has published h0[t] (flag t+1)
            if (wave == 0)
                poll_flags(ownF, (uint32_t)t, crossF, (uint32_t)(t + 1), lane);
            __syncthreads();
            // ---- stage h1[t-1] (parity) + h0[t] (ring slot t&7)
            {
                const uint32_t* hb = h1i + (size_t)((t + 1) & 1) * 2048;
                const uint32_t* gb = h0i + (size_t)(t & 7) * 2048;
                uint32_t va[8], vb[8];
#pragma unroll
                for (int i = 0; i < 8; ++i) va[i] = ald(hb + i * 256 + tid);
#pragma unroll
                for (int i = 0; i < 8; ++i) vb[i] = ald(gb + i * 256 + tid);
#pragma unroll
                for (int i = 0; i < 8; ++i) {
                    const int u = i * 256 + tid;
                    *(uint32_t*)&bl0[u >> 8][(u & 255) * 2] = va[i];
                    *(uint32_t*)&bl1[u >> 8][(u & 255) * 2] = vb[i];
                }
            }
            __syncthreads();
            // ---- MFMA: 2 tiles x (16+16); shared B loads; 8 indep chains
            floatx4 acc[2][4] = {};
            {
                const f16* br0 = &bl0[hrow][quad * 8];
                const f16* br1 = &bl1[hrow][quad * 8];
#pragma unroll
                for (int kk = 0; kk < 16; ++kk) {
                    const half8 b0v = *(const half8*)(br0 + kk * 32);
                    const half8 b1v = *(const half8*)(br1 + kk * 32);
                    acc[0][kk & 3] = __builtin_amdgcn_mfma_f32_16x16x32_f16(
                        ah[0][kk], b0v, acc[0][kk & 3], 0, 0, 0);
                    acc[1][kk & 3] = __builtin_amdgcn_mfma_f32_16x16x32_f16(
                        ah[1][kk], b0v, acc[1][kk & 3], 0, 0, 0);
                    acc[0][kk & 3] = __builtin_amdgcn_mfma_f32_16x16x32_f16(
                        ai[0][kk], b1v, acc[0][kk & 3], 0, 0, 0);
                    acc[1][kk & 3] = __builtin_amdgcn_mfma_f32_16x16x32_f16(
                        ai[1][kk], b1v, acc[1][kk & 3], 0, 0, 0);
                }
            }
#pragma unroll
            for (int tt = 0; tt < 2; ++tt) {
                const floatx4 av = (acc[tt][0] + acc[tt][1]) + (acc[tt][2] + acc[tt][3]);
                const float hn = lstm_cell(av[0] + bias[tt][0], av[1] + bias[tt][1],
                                           av[2] + bias[tt][2], av[3] + bias[tt][3],
                                           c[tt]);
                const float ho = __shfl_xor(hn, 16);
                if (!(quad & 1) && lm < 8) {
                    union { f16 h[2]; uint32_t u; } pk;
                    pk.h[0] = (f16)hn; pk.h[1] = (f16)ho;
                    ast(h1i + (size_t)(t & 1) * 2048 +
                        (lm * H_ + jw + tt * 4 + quad) / 2, pk.u);
                }
                if (t == T_ - 1 && lm < 8)
                    dout[(size_t)(b0 + lm) * H_ + jw + tt * 4 + quad] = hn;
            }
            __syncthreads();                       // drains h stores (vmcnt 0)
            if (tid == 0) ast(ownF + mem * 16, (uint32_t)(t + 1));
        }
    }
}

// ------------------------------------------------------------ launcher ------
extern "C" void kernel_launch(void* const* d_in, const int* in_sizes, int n_in,
                              void* d_out, int out_size, void* d_ws, size_t ws_size,
                              hipStream_t stream) {
    const float* x    = (const float*)d_in[0];
    const float* Wih0 = (const float*)d_in[1];
    const float* Whh0 = (const float*)d_in[2];
    const float* bih0 = (const float*)d_in[3];
    const float* bhh0 = (const float*)d_in[4];
    const float* mih0 = (const float*)d_in[5];
    const float* mhh0 = (const float*)d_in[6];
    const float* Wih1 = (const float*)d_in[7];
    const float* Whh1 = (const float*)d_in[8];
    const float* bih1 = (const float*)d_in[9];
    const float* bhh1 = (const float*)d_in[10];
    const float* mih1 = (const float*)d_in[11];
    const float* mhh1 = (const float*)d_in[12];

    char* ws = (char*)d_ws;
    uint32_t* flags = (uint32_t*)(ws + OFF_FLAGS);
    uint32_t* h0b   = (uint32_t*)(ws + OFF_H0B);
    uint32_t* h1b   = (uint32_t*)(ws + OFF_H1B);
    f16*   wih0 = (f16*)(ws + OFF_WIH0);
    f16*   whh0 = (f16*)(ws + OFF_WHH0);
    f16*   wih1 = (f16*)(ws + OFF_WIH1);
    f16*   whh1 = (f16*)(ws + OFF_WHH1);
    float* bs0  = (float*)(ws + OFF_B0);
    float* bs1  = (float*)(ws + OFF_B1);
    float* out  = (float*)d_out;

    // zero flags + h rings (ws is re-poisoned before every timed call)
    hipMemsetAsync(ws, 0, ZERO_BYTES, stream);

    k_maskw<<<512,  256, 0, stream>>>(Wih0, mih0, wih0, G_ * DIN_ / 4);
    k_maskw<<<1024, 256, 0, stream>>>(Whh0, mhh0, whh0, G_ * H_ / 4);
    k_maskw<<<1024, 256, 0, stream>>>(Wih1, mih1, wih1, G_ * H_ / 4);
    k_maskw<<<1024, 256, 0, stream>>>(Whh1, mhh1, whh1, G_ * H_ / 4);
    k_bias<<<8, 256, 0, stream>>>(bih0, bhh0, bs0);
    k_bias<<<8, 256, 0, stream>>>(bih1, bhh1, bs1);

    fused_rnn<<<256, 256, 0, stream>>>(x, wih0, whh0, bs0, wih1, whh1, bs1,
                                       out, h0b, h1b, flags);

    (void)in_sizes; (void)n_in; (void)out_size; (void)ws_size;
}